// Round 8
// baseline (128.363 us; speedup 1.0000x reference)
//
#include <hip/hip_runtime.h>

#define BB 1024
#define TT 512
#define KK 64
#define CH 8   // scan steps per chunk

typedef float f32x4 __attribute__((ext_vector_type(4)));

__device__ __forceinline__ float lane_bcast(float v, int lane) {
    return __uint_as_float(__builtin_amdgcn_readlane(__float_as_uint(v), lane));
}

__device__ __forceinline__ float wave_sum(float v) {
#pragma unroll
    for (int off = 1; off < 64; off <<= 1) v += __shfl_xor(v, off);
    return v;
}

__device__ __forceinline__ float wave_max(float v) {
#pragma unroll
    for (int off = 1; off < 64; off <<= 1) v = fmaxf(v, __shfl_xor(v, off));
    return v;
}

// One wave per batch element; lane j owns state j. Exactly 1 wave/SIMD at
// grid=1024, so amdgpu_waves_per_eu(1,1) is free and gives the allocator the
// full 512-VGPR budget (rounds 6/7: default 8-wave target spilled E to
// scratch, VGPR_Count=56). The asm anchor in the loop forces E0..E15 live in
// VGPRs every iteration (anti-spill/remat).
__global__ void __launch_bounds__(64)
__attribute__((amdgpu_waves_per_eu(1, 1)))
crf_fwd(
    const float* __restrict__ logits,
    const float* __restrict__ trans,
    const int* __restrict__ gold,
    const int* __restrict__ seq_len,
    float* __restrict__ ws)
{
    const int b = blockIdx.x;
    const int j = threadIdx.x & 63;
    const float* lg = logits + (size_t)b * (TT * KK);
    const int* gd = gold + (size_t)b * TT;
    const int L = seq_len[b];

    // ---- Phase A: lane-parallel first & second terms (off the scan) ----
    float af = 0.0f, asec = 0.0f;
#pragma unroll
    for (int c = 0; c < TT / 64; ++c) {
        int t = c * 64 + j;
        if (t < L) {
            int g0 = gd[t];
            af += lg[t * KK + g0];
            if (t + 1 < L) {
                int g1 = gd[t + 1];
                asec += trans[g0 * KK + g1];
            }
        }
    }

    // ---- E rows: 16 x f32x4 in registers ----
    const f32x4* Et = reinterpret_cast<const f32x4*>(trans) + (size_t)j * (KK / 4);
#define DECLE(q) f32x4 E##q = Et[q]; \
    E##q.x = __expf(E##q.x); E##q.y = __expf(E##q.y); \
    E##q.z = __expf(E##q.z); E##q.w = __expf(E##q.w);
    DECLE(0)  DECLE(1)  DECLE(2)  DECLE(3)
    DECLE(4)  DECLE(5)  DECLE(6)  DECLE(7)
    DECLE(8)  DECLE(9)  DECLE(10) DECLE(11)
    DECLE(12) DECLE(13) DECLE(14) DECLE(15)
#undef DECLE

    // ---- t = 0 init ----
    float a0 = lg[j];
    float mx = wave_max(a0);
    float p = __expf(a0 - mx);   // unnormalized; scale absorbed at checkpoints
    float m = mx;

    // ---- preload chunk 0 (t = 1..8) ----
    f32x4 nl0, nl1;
    nl0.x = lg[1 * KK + j]; nl0.y = lg[2 * KK + j];
    nl0.z = lg[3 * KK + j]; nl0.w = lg[4 * KK + j];
    nl1.x = lg[5 * KK + j]; nl1.y = lg[6 * KK + j];
    nl1.z = lg[7 * KK + j]; nl1.w = lg[8 * KK + j];

#define MACQ(q) \
    s0 = fmaf(E##q.x, lane_bcast(p, (q) * 4 + 0), s0); \
    s1 = fmaf(E##q.y, lane_bcast(p, (q) * 4 + 1), s1); \
    s2 = fmaf(E##q.z, lane_bcast(p, (q) * 4 + 2), s2); \
    s3 = fmaf(E##q.w, lane_bcast(p, (q) * 4 + 3), s3);

#define STEP(ii, EL) { \
    float s0 = 0.f, s1 = 0.f, s2 = 0.f, s3 = 0.f; \
    MACQ(0)  MACQ(1)  MACQ(2)  MACQ(3) \
    MACQ(4)  MACQ(5)  MACQ(6)  MACQ(7) \
    MACQ(8)  MACQ(9)  MACQ(10) MACQ(11) \
    MACQ(12) MACQ(13) MACQ(14) MACQ(15) \
    float s = (s0 + s1) + (s2 + s3); \
    float pn = s * (EL); \
    p = (t0 + (ii) < L) ? pn : p; }

    // ---- sequential scan, chunks of CH=8 fully-unrolled steps ----
    for (int t0 = 1; t0 < L; t0 += CH) {
        // Force E0..E15 (64 VGPRs) live-in-register at every iteration:
        // spilling them now costs reload-per-iter, so the allocator keeps them.
        asm volatile("" : "+v"(E0), "+v"(E1), "+v"(E2), "+v"(E3),
                          "+v"(E4), "+v"(E5), "+v"(E6), "+v"(E7),
                          "+v"(E8), "+v"(E9), "+v"(E10), "+v"(E11),
                          "+v"(E12), "+v"(E13), "+v"(E14), "+v"(E15));

        // exp of current chunk's logits (off the critical p-chain)
        f32x4 el0, el1;
        el0.x = __expf(nl0.x); el0.y = __expf(nl0.y);
        el0.z = __expf(nl0.z); el0.w = __expf(nl0.w);
        el1.x = __expf(nl1.x); el1.y = __expf(nl1.y);
        el1.z = __expf(nl1.z); el1.w = __expf(nl1.w);

        // prefetch next chunk (consumed one full chunk later)
        {
            int tn = t0 + CH;
            int c0 = tn + 0; c0 = (c0 > TT - 1) ? TT - 1 : c0;
            int c1 = tn + 1; c1 = (c1 > TT - 1) ? TT - 1 : c1;
            int c2 = tn + 2; c2 = (c2 > TT - 1) ? TT - 1 : c2;
            int c3 = tn + 3; c3 = (c3 > TT - 1) ? TT - 1 : c3;
            int c4 = tn + 4; c4 = (c4 > TT - 1) ? TT - 1 : c4;
            int c5 = tn + 5; c5 = (c5 > TT - 1) ? TT - 1 : c5;
            int c6 = tn + 6; c6 = (c6 > TT - 1) ? TT - 1 : c6;
            int c7 = tn + 7; c7 = (c7 > TT - 1) ? TT - 1 : c7;
            nl0.x = lg[c0 * KK + j]; nl0.y = lg[c1 * KK + j];
            nl0.z = lg[c2 * KK + j]; nl0.w = lg[c3 * KK + j];
            nl1.x = lg[c4 * KK + j]; nl1.y = lg[c5 * KK + j];
            nl1.z = lg[c6 * KK + j]; nl1.w = lg[c7 * KK + j];
        }

        STEP(0, el0.x) STEP(1, el0.y) STEP(2, el0.z) STEP(3, el0.w)
        STEP(4, el1.x) STEP(5, el1.y) STEP(6, el1.z) STEP(7, el1.w)

        // cheap checkpoint renorm: divide by p[0] (any positive reference;
        // scale absorbed exactly into m). p[0] >= e^{-spread} * max(p),
        // spread is O(10); chunk growth stays far below fp32 max.
        float c = lane_bcast(p, 0);
        p *= (1.0f / c);
        m += __logf(c);
    }
#undef STEP
#undef MACQ

    float sump = wave_sum(p);
    float third_b = m + __logf(sump);
    float first_b = wave_sum(af);
    float second_b = wave_sum(asec);

    if (j == 0) {
        ws[b] = (third_b - first_b - second_b) * (1.0f / (float)BB);
    }
}

// Deterministic fixed-order reduction of the 1024 per-b contributions.
__global__ void crf_reduce(const float* __restrict__ ws, float* __restrict__ out) {
    int tid = threadIdx.x;  // 256 threads
    float v = ws[tid] + ws[tid + 256] + ws[tid + 512] + ws[tid + 768];
    v = wave_sum(v);
    __shared__ float sm[4];
    if ((tid & 63) == 0) sm[tid >> 6] = v;
    __syncthreads();
    if (tid == 0) out[0] = (sm[0] + sm[1]) + (sm[2] + sm[3]);
}

extern "C" void kernel_launch(void* const* d_in, const int* in_sizes, int n_in,
                              void* d_out, int out_size, void* d_ws, size_t ws_size,
                              hipStream_t stream) {
    const float* logits = (const float*)d_in[0];
    const float* trans  = (const float*)d_in[1];
    const int*   gold   = (const int*)d_in[2];
    const int*   slen   = (const int*)d_in[3];
    float* out = (float*)d_out;
    float* ws = (float*)d_ws;

    hipLaunchKernelGGL(crf_fwd, dim3(BB), dim3(64), 0, stream,
                       logits, trans, gold, slen, ws);
    hipLaunchKernelGGL(crf_reduce, dim3(1), dim3(256), 0, stream, ws, out);
}

// Round 9
// 128.269 us; speedup vs baseline: 1.0007x; 1.0007x over previous
//
#include <hip/hip_runtime.h>

#define BB 1024
#define TT 512
#define KK 64
#define CH 8   // scan steps per chunk

typedef float f32x4 __attribute__((ext_vector_type(4)));

__device__ __forceinline__ float lane_bcast(float v, int lane) {
    return __uint_as_float(__builtin_amdgcn_readlane(__float_as_uint(v), lane));
}

__device__ __forceinline__ float wave_sum(float v) {
#pragma unroll
    for (int off = 1; off < 64; off <<= 1) v += __shfl_xor(v, off);
    return v;
}

__device__ __forceinline__ float wave_max(float v) {
#pragma unroll
    for (int off = 1; off < 64; off <<= 1) v = fmaxf(v, __shfl_xor(v, off));
    return v;
}

// One wave per batch element; lane j owns state j. 1 wave/SIMD at grid=1024,
// so waves_per_eu(1,1) is free (full VGPR budget; round 8 verified E resident,
// VGPR_Count=132). Round-8 lesson: the stall is the readlane->fma SGPR
// hazard chain; broadcasts are now HOISTED in groups of 32 so each v_readlane
// and its consuming v_fma are ~31 instructions apart.
__global__ void __launch_bounds__(64)
__attribute__((amdgpu_waves_per_eu(1, 1)))
crf_fwd(
    const float* __restrict__ logits,
    const float* __restrict__ trans,
    const int* __restrict__ gold,
    const int* __restrict__ seq_len,
    float* __restrict__ ws)
{
    const int b = blockIdx.x;
    const int j = threadIdx.x & 63;
    const float* lg = logits + (size_t)b * (TT * KK);
    const int* gd = gold + (size_t)b * TT;
    const int L = seq_len[b];

    // ---- Phase A: lane-parallel first & second terms (off the scan) ----
    float af = 0.0f, asec = 0.0f;
#pragma unroll
    for (int c = 0; c < TT / 64; ++c) {
        int t = c * 64 + j;
        if (t < L) {
            int g0 = gd[t];
            af += lg[t * KK + g0];
            if (t + 1 < L) {
                int g1 = gd[t + 1];
                asec += trans[g0 * KK + g1];
            }
        }
    }

    // ---- E rows: 16 x f32x4 in registers ----
    const f32x4* Et = reinterpret_cast<const f32x4*>(trans) + (size_t)j * (KK / 4);
#define DECLE(q) f32x4 E##q = Et[q]; \
    E##q.x = __expf(E##q.x); E##q.y = __expf(E##q.y); \
    E##q.z = __expf(E##q.z); E##q.w = __expf(E##q.w);
    DECLE(0)  DECLE(1)  DECLE(2)  DECLE(3)
    DECLE(4)  DECLE(5)  DECLE(6)  DECLE(7)
    DECLE(8)  DECLE(9)  DECLE(10) DECLE(11)
    DECLE(12) DECLE(13) DECLE(14) DECLE(15)
#undef DECLE

    // ---- t = 0 init ----
    float a0 = lg[j];
    float mx = wave_max(a0);
    float p = __expf(a0 - mx);   // unnormalized; scale absorbed at checkpoints
    float m = mx;

    // ---- preload chunk 0 (t = 1..8) ----
    f32x4 nl0, nl1;
    nl0.x = lg[1 * KK + j]; nl0.y = lg[2 * KK + j];
    nl0.z = lg[3 * KK + j]; nl0.w = lg[4 * KK + j];
    nl1.x = lg[5 * KK + j]; nl1.y = lg[6 * KK + j];
    nl1.z = lg[7 * KK + j]; nl1.w = lg[8 * KK + j];

    // broadcast quad for MFMA-free matvec: quad q supplies p[4q..4q+3]
#define BQ(q) \
    float bq##q##_0 = lane_bcast(p, (q) * 4 + 0); \
    float bq##q##_1 = lane_bcast(p, (q) * 4 + 1); \
    float bq##q##_2 = lane_bcast(p, (q) * 4 + 2); \
    float bq##q##_3 = lane_bcast(p, (q) * 4 + 3);

#define MQ(q) \
    s0 = fmaf(E##q.x, bq##q##_0, s0); \
    s1 = fmaf(E##q.y, bq##q##_1, s1); \
    s2 = fmaf(E##q.z, bq##q##_2, s2); \
    s3 = fmaf(E##q.w, bq##q##_3, s3);

    // 32 hoisted broadcasts, then their 32 FMAs, then the next 32+32:
    // producer->consumer separation ~31 instrs kills the SGPR-read hazard.
#define STEP(ii, EL) { \
    float s0 = 0.f, s1 = 0.f, s2 = 0.f, s3 = 0.f; \
    BQ(0) BQ(1) BQ(2) BQ(3) BQ(4) BQ(5) BQ(6) BQ(7) \
    MQ(0) MQ(1) MQ(2) MQ(3) MQ(4) MQ(5) MQ(6) MQ(7) \
    BQ(8) BQ(9) BQ(10) BQ(11) BQ(12) BQ(13) BQ(14) BQ(15) \
    MQ(8) MQ(9) MQ(10) MQ(11) MQ(12) MQ(13) MQ(14) MQ(15) \
    float s = (s0 + s1) + (s2 + s3); \
    float pn = s * (EL); \
    p = (t0 + (ii) < L) ? pn : p; }

    // ---- sequential scan, chunks of CH=8 fully-unrolled steps ----
    for (int t0 = 1; t0 < L; t0 += CH) {
        // Force E0..E15 live-in-register at every iteration (anti-spill).
        asm volatile("" : "+v"(E0), "+v"(E1), "+v"(E2), "+v"(E3),
                          "+v"(E4), "+v"(E5), "+v"(E6), "+v"(E7),
                          "+v"(E8), "+v"(E9), "+v"(E10), "+v"(E11),
                          "+v"(E12), "+v"(E13), "+v"(E14), "+v"(E15));

        // exp of current chunk's logits (off the critical p-chain)
        f32x4 el0, el1;
        el0.x = __expf(nl0.x); el0.y = __expf(nl0.y);
        el0.z = __expf(nl0.z); el0.w = __expf(nl0.w);
        el1.x = __expf(nl1.x); el1.y = __expf(nl1.y);
        el1.z = __expf(nl1.z); el1.w = __expf(nl1.w);

        // prefetch next chunk (consumed one full chunk later)
        {
            int tn = t0 + CH;
            int c0 = tn + 0; c0 = (c0 > TT - 1) ? TT - 1 : c0;
            int c1 = tn + 1; c1 = (c1 > TT - 1) ? TT - 1 : c1;
            int c2 = tn + 2; c2 = (c2 > TT - 1) ? TT - 1 : c2;
            int c3 = tn + 3; c3 = (c3 > TT - 1) ? TT - 1 : c3;
            int c4 = tn + 4; c4 = (c4 > TT - 1) ? TT - 1 : c4;
            int c5 = tn + 5; c5 = (c5 > TT - 1) ? TT - 1 : c5;
            int c6 = tn + 6; c6 = (c6 > TT - 1) ? TT - 1 : c6;
            int c7 = tn + 7; c7 = (c7 > TT - 1) ? TT - 1 : c7;
            nl0.x = lg[c0 * KK + j]; nl0.y = lg[c1 * KK + j];
            nl0.z = lg[c2 * KK + j]; nl0.w = lg[c3 * KK + j];
            nl1.x = lg[c4 * KK + j]; nl1.y = lg[c5 * KK + j];
            nl1.z = lg[c6 * KK + j]; nl1.w = lg[c7 * KK + j];
        }

        STEP(0, el0.x) STEP(1, el0.y) STEP(2, el0.z) STEP(3, el0.w)
        STEP(4, el1.x) STEP(5, el1.y) STEP(6, el1.z) STEP(7, el1.w)

        // cheap checkpoint renorm: divide by p[0] (any positive reference;
        // scale absorbed exactly into m).
        float c = lane_bcast(p, 0);
        p *= (1.0f / c);
        m += __logf(c);
    }
#undef STEP
#undef MQ
#undef BQ

    float sump = wave_sum(p);
    float third_b = m + __logf(sump);
    float first_b = wave_sum(af);
    float second_b = wave_sum(asec);

    if (j == 0) {
        ws[b] = (third_b - first_b - second_b) * (1.0f / (float)BB);
    }
}

// Deterministic fixed-order reduction of the 1024 per-b contributions.
__global__ void crf_reduce(const float* __restrict__ ws, float* __restrict__ out) {
    int tid = threadIdx.x;  // 256 threads
    float v = ws[tid] + ws[tid + 256] + ws[tid + 512] + ws[tid + 768];
    v = wave_sum(v);
    __shared__ float sm[4];
    if ((tid & 63) == 0) sm[tid >> 6] = v;
    __syncthreads();
    if (tid == 0) out[0] = (sm[0] + sm[1]) + (sm[2] + sm[3]);
}

extern "C" void kernel_launch(void* const* d_in, const int* in_sizes, int n_in,
                              void* d_out, int out_size, void* d_ws, size_t ws_size,
                              hipStream_t stream) {
    const float* logits = (const float*)d_in[0];
    const float* trans  = (const float*)d_in[1];
    const int*   gold   = (const int*)d_in[2];
    const int*   slen   = (const int*)d_in[3];
    float* out = (float*)d_out;
    float* ws = (float*)d_ws;

    hipLaunchKernelGGL(crf_fwd, dim3(BB), dim3(64), 0, stream,
                       logits, trans, gold, slen, ws);
    hipLaunchKernelGGL(crf_reduce, dim3(1), dim3(256), 0, stream, ws, out);
}

// Round 10
// 108.525 us; speedup vs baseline: 1.1828x; 1.1819x over previous
//
#include <hip/hip_runtime.h>

#define BB 1024
#define TT 512
#define KK 64
#define CH 8   // scan steps per chunk

typedef float f32x4 __attribute__((ext_vector_type(4)));
typedef float f32x2 __attribute__((ext_vector_type(2)));

__device__ __forceinline__ float lane_bcast(float v, int lane) {
    return __uint_as_float(__builtin_amdgcn_readlane(__float_as_uint(v), lane));
}

__device__ __forceinline__ float wave_sum(float v) {
#pragma unroll
    for (int off = 1; off < 64; off <<= 1) v += __shfl_xor(v, off);
    return v;
}

__device__ __forceinline__ float wave_max(float v) {
#pragma unroll
    for (int off = 1; off < 64; off <<= 1) v = fmaxf(v, __shfl_xor(v, off));
    return v;
}

#define LO2(v4) __builtin_shufflevector((v4), (v4), 0, 1)
#define HI2(v4) __builtin_shufflevector((v4), (v4), 2, 3)

// One wave per batch element; lane j owns state j. 1 wave/SIMD at grid=1024.
// Rounds 7-9 lesson: a lone wave issues ~1 instr / 4.9 cy (single-wave issue
// cadence); we are instruction-COUNT-bound. This version cuts the step from
// ~135 to ~56 instrs: p broadcast via uniform-address ds_read_b128 (4 values
// per instr, replaces 64 v_readlane) and packed f32 FMA (v_pk_fma_f32, 2
// MACs per instr).
__global__ void __launch_bounds__(64)
__attribute__((amdgpu_waves_per_eu(1, 1)))
crf_fwd(
    const float* __restrict__ logits,
    const float* __restrict__ trans,
    const int* __restrict__ gold,
    const int* __restrict__ seq_len,
    float* __restrict__ ws)
{
    __shared__ float plds[KK];           // broadcast buffer: p[0..63]
    const int b = blockIdx.x;
    const int j = threadIdx.x & 63;
    const float* lg = logits + (size_t)b * (TT * KK);
    const int* gd = gold + (size_t)b * TT;
    const int L = seq_len[b];

    // ---- Phase A: lane-parallel first & second terms (off the scan) ----
    float af = 0.0f, asec = 0.0f;
#pragma unroll
    for (int c = 0; c < TT / 64; ++c) {
        int t = c * 64 + j;
        if (t < L) {
            int g0 = gd[t];
            af += lg[t * KK + g0];
            if (t + 1 < L) {
                int g1 = gd[t + 1];
                asec += trans[g0 * KK + g1];
            }
        }
    }

    // ---- E rows: 16 x f32x4 in registers (row j per lane) ----
    const f32x4* Et = reinterpret_cast<const f32x4*>(trans) + (size_t)j * (KK / 4);
#define DECLE(q) f32x4 E##q = Et[q]; \
    E##q.x = __expf(E##q.x); E##q.y = __expf(E##q.y); \
    E##q.z = __expf(E##q.z); E##q.w = __expf(E##q.w);
    DECLE(0)  DECLE(1)  DECLE(2)  DECLE(3)
    DECLE(4)  DECLE(5)  DECLE(6)  DECLE(7)
    DECLE(8)  DECLE(9)  DECLE(10) DECLE(11)
    DECLE(12) DECLE(13) DECLE(14) DECLE(15)
#undef DECLE

    // ---- t = 0 init ----
    float a0 = lg[j];
    float mx = wave_max(a0);
    float p = __expf(a0 - mx);   // unnormalized; scale absorbed at checkpoints
    float m = mx;
    plds[j] = p;                 // publish initial p (single wave: DS in-order)

    // ---- preload chunk 0 (t = 1..8) ----
    f32x4 nl0, nl1;
    nl0.x = lg[1 * KK + j]; nl0.y = lg[2 * KK + j];
    nl0.z = lg[3 * KK + j]; nl0.w = lg[4 * KK + j];
    nl1.x = lg[5 * KK + j]; nl1.y = lg[6 * KK + j];
    nl1.z = lg[7 * KK + j]; nl1.w = lg[8 * KK + j];

    const f32x4* pl4 = reinterpret_cast<const f32x4*>(plds);

    // MAC quad q: 2 packed FMAs (E quad x broadcast quad) into rotating accs
#define MQ(q, Q, A, B) \
    A = __builtin_elementwise_fma(LO2(E##q), LO2(Q), A); \
    B = __builtin_elementwise_fma(HI2(E##q), HI2(Q), B);

#define STEP(ii, EL) { \
    f32x4 Q0 = pl4[0],  Q1 = pl4[1],  Q2 = pl4[2],  Q3 = pl4[3]; \
    f32x4 Q4 = pl4[4],  Q5 = pl4[5],  Q6 = pl4[6],  Q7 = pl4[7]; \
    f32x4 Q8 = pl4[8],  Q9 = pl4[9],  Q10 = pl4[10], Q11 = pl4[11]; \
    f32x4 Q12 = pl4[12], Q13 = pl4[13], Q14 = pl4[14], Q15 = pl4[15]; \
    f32x2 aA = {0.f, 0.f}, aB = {0.f, 0.f}, aC = {0.f, 0.f}, aD = {0.f, 0.f}; \
    MQ(0,  Q0,  aA, aB) MQ(1,  Q1,  aC, aD) \
    MQ(2,  Q2,  aA, aB) MQ(3,  Q3,  aC, aD) \
    MQ(4,  Q4,  aA, aB) MQ(5,  Q5,  aC, aD) \
    MQ(6,  Q6,  aA, aB) MQ(7,  Q7,  aC, aD) \
    MQ(8,  Q8,  aA, aB) MQ(9,  Q9,  aC, aD) \
    MQ(10, Q10, aA, aB) MQ(11, Q11, aC, aD) \
    MQ(12, Q12, aA, aB) MQ(13, Q13, aC, aD) \
    MQ(14, Q14, aA, aB) MQ(15, Q15, aC, aD) \
    aA = aA + aC; aB = aB + aD; aA = aA + aB; \
    float s = aA.x + aA.y; \
    float pn = s * (EL); \
    p = (t0 + (ii) < L) ? pn : p; \
    plds[j] = p; }

    // ---- sequential scan, chunks of CH=8 fully-unrolled steps ----
    for (int t0 = 1; t0 < L; t0 += CH) {
        // Force E0..E15 live-in-register every iteration (anti-spill).
        asm volatile("" : "+v"(E0), "+v"(E1), "+v"(E2), "+v"(E3),
                          "+v"(E4), "+v"(E5), "+v"(E6), "+v"(E7),
                          "+v"(E8), "+v"(E9), "+v"(E10), "+v"(E11),
                          "+v"(E12), "+v"(E13), "+v"(E14), "+v"(E15));

        // exp of current chunk's logits (off the critical p-chain)
        f32x4 el0, el1;
        el0.x = __expf(nl0.x); el0.y = __expf(nl0.y);
        el0.z = __expf(nl0.z); el0.w = __expf(nl0.w);
        el1.x = __expf(nl1.x); el1.y = __expf(nl1.y);
        el1.z = __expf(nl1.z); el1.w = __expf(nl1.w);

        // prefetch next chunk (consumed one full chunk later)
        {
            int tn = t0 + CH;
            int c0 = tn + 0; c0 = (c0 > TT - 1) ? TT - 1 : c0;
            int c1 = tn + 1; c1 = (c1 > TT - 1) ? TT - 1 : c1;
            int c2 = tn + 2; c2 = (c2 > TT - 1) ? TT - 1 : c2;
            int c3 = tn + 3; c3 = (c3 > TT - 1) ? TT - 1 : c3;
            int c4 = tn + 4; c4 = (c4 > TT - 1) ? TT - 1 : c4;
            int c5 = tn + 5; c5 = (c5 > TT - 1) ? TT - 1 : c5;
            int c6 = tn + 6; c6 = (c6 > TT - 1) ? TT - 1 : c6;
            int c7 = tn + 7; c7 = (c7 > TT - 1) ? TT - 1 : c7;
            nl0.x = lg[c0 * KK + j]; nl0.y = lg[c1 * KK + j];
            nl0.z = lg[c2 * KK + j]; nl0.w = lg[c3 * KK + j];
            nl1.x = lg[c4 * KK + j]; nl1.y = lg[c5 * KK + j];
            nl1.z = lg[c6 * KK + j]; nl1.w = lg[c7 * KK + j];
        }

        STEP(0, el0.x) STEP(1, el0.y) STEP(2, el0.z) STEP(3, el0.w)
        STEP(4, el1.x) STEP(5, el1.y) STEP(6, el1.z) STEP(7, el1.w)

        // cheap checkpoint renorm: divide by p[0] (positive reference; scale
        // absorbed exactly into m). Republish scaled p to LDS.
        float c = lane_bcast(p, 0);
        p *= (1.0f / c);
        m += __logf(c);
        plds[j] = p;
    }
#undef STEP
#undef MQ

    float sump = wave_sum(p);
    float third_b = m + __logf(sump);
    float first_b = wave_sum(af);
    float second_b = wave_sum(asec);

    if (j == 0) {
        ws[b] = (third_b - first_b - second_b) * (1.0f / (float)BB);
    }
}

// Deterministic fixed-order reduction of the 1024 per-b contributions.
__global__ void crf_reduce(const float* __restrict__ ws, float* __restrict__ out) {
    int tid = threadIdx.x;  // 256 threads
    float v = ws[tid] + ws[tid + 256] + ws[tid + 512] + ws[tid + 768];
    v = wave_sum(v);
    __shared__ float sm[4];
    if ((tid & 63) == 0) sm[tid >> 6] = v;
    __syncthreads();
    if (tid == 0) out[0] = (sm[0] + sm[1]) + (sm[2] + sm[3]);
}

extern "C" void kernel_launch(void* const* d_in, const int* in_sizes, int n_in,
                              void* d_out, int out_size, void* d_ws, size_t ws_size,
                              hipStream_t stream) {
    const float* logits = (const float*)d_in[0];
    const float* trans  = (const float*)d_in[1];
    const int*   gold   = (const int*)d_in[2];
    const int*   slen   = (const int*)d_in[3];
    float* out = (float*)d_out;
    float* ws = (float*)d_ws;

    hipLaunchKernelGGL(crf_fwd, dim3(BB), dim3(64), 0, stream,
                       logits, trans, gold, slen, ws);
    hipLaunchKernelGGL(crf_reduce, dim3(1), dim3(256), 0, stream, ws, out);
}

// Round 11
// 103.601 us; speedup vs baseline: 1.2390x; 1.0475x over previous
//
#include <hip/hip_runtime.h>

#define BB 1024
#define TT 512
#define KK 64
#define CH 8   // scan steps per chunk

typedef _Float16 f16x2 __attribute__((ext_vector_type(2)));
typedef float f32x4 __attribute__((ext_vector_type(4)));
typedef unsigned int u32x4 __attribute__((ext_vector_type(4)));

__device__ __forceinline__ float wave_sum(float v) {
#pragma unroll
    for (int off = 1; off < 64; off <<= 1) v += __shfl_xor(v, off);
    return v;
}

__device__ __forceinline__ float wave_max(float v) {
#pragma unroll
    for (int off = 1; off < 64; off <<= 1) v = fmaxf(v, __shfl_xor(v, off));
    return v;
}

#if __has_builtin(__builtin_amdgcn_fdot2)
#define FDOT2(E, P, A) __builtin_amdgcn_fdot2((E), (P), (A), false)
#else
__device__ __forceinline__ float fdot2_emul(f16x2 e, f16x2 p, float a) {
    return fmaf((float)e.x, (float)p.x, fmaf((float)e.y, (float)p.y, a));
}
#define FDOT2(E, P, A) fdot2_emul((E), (P), (A))
#endif

// One wave per batch element; lane j owns state j. 1 wave/SIMD at grid=1024.
// Round-10 model: per-step cost = LDS broadcast (16 b128) + round-trip
// latency. This version: p stored in LDS as f16 (8 b128 reads), matvec via
// v_dot2_f32_f16 (2 MAC/instr, f32 accum). f16 range handled by per-step
// EXACT power-of-2 rescale: e = exponent(pn[lane0]), p *= 2^-e, Etot += e.
// third = mx + Etot*ln2 + log(sum p). State spread ~e^±8 = 2^±11.5 fits f16.
__global__ void __launch_bounds__(64)
__attribute__((amdgpu_waves_per_eu(1, 1)))
crf_fwd(
    const float* __restrict__ logits,
    const float* __restrict__ trans,
    const int* __restrict__ gold,
    const int* __restrict__ seq_len,
    float* __restrict__ ws)
{
    __shared__ __align__(16) _Float16 plds[KK];   // p broadcast buffer (f16)
    const int b = blockIdx.x;
    const int j = threadIdx.x & 63;
    const float* lg = logits + (size_t)b * (TT * KK);
    const int* gd = gold + (size_t)b * TT;
    const int L = seq_len[b];

    // ---- Phase A: lane-parallel first & second terms (off the scan) ----
    float af = 0.0f, asec = 0.0f;
#pragma unroll
    for (int c = 0; c < TT / 64; ++c) {
        int t = c * 64 + j;
        if (t < L) {
            int g0 = gd[t];
            af += lg[t * KK + g0];
            if (t + 1 < L) {
                int g1 = gd[t + 1];
                asec += trans[g0 * KK + g1];
            }
        }
    }

    // ---- E row j as 32 named packed f16x2 (RNE casts, unbiased) ----
    const float* Ej = trans + (size_t)j * KK;
#define DECLE(q) f16x2 Eh##q; { \
    float e0 = __expf(Ej[2 * (q)]); float e1 = __expf(Ej[2 * (q) + 1]); \
    Eh##q.x = (_Float16)e0; Eh##q.y = (_Float16)e1; }
    DECLE(0)  DECLE(1)  DECLE(2)  DECLE(3)  DECLE(4)  DECLE(5)  DECLE(6)  DECLE(7)
    DECLE(8)  DECLE(9)  DECLE(10) DECLE(11) DECLE(12) DECLE(13) DECLE(14) DECLE(15)
    DECLE(16) DECLE(17) DECLE(18) DECLE(19) DECLE(20) DECLE(21) DECLE(22) DECLE(23)
    DECLE(24) DECLE(25) DECLE(26) DECLE(27) DECLE(28) DECLE(29) DECLE(30) DECLE(31)
#undef DECLE

    // ---- t = 0 init ----
    float a0 = lg[j];
    float mx = wave_max(a0);
    float p0 = __expf(a0 - mx);          // in (e^-spread, 1], fits f16
    _Float16 h0 = (_Float16)p0;
    float pq = (float)h0;                // dequantized running p (own state)
    plds[j] = h0;
    int Etot = 0;

    // ---- preload chunk 0 (t = 1..8) ----
    f32x4 nl0, nl1;
    nl0.x = lg[1 * KK + j]; nl0.y = lg[2 * KK + j];
    nl0.z = lg[3 * KK + j]; nl0.w = lg[4 * KK + j];
    nl1.x = lg[5 * KK + j]; nl1.y = lg[6 * KK + j];
    nl1.z = lg[7 * KK + j]; nl1.w = lg[8 * KK + j];

#define DOTQ(q, W, A) A = FDOT2(Eh##q, __builtin_bit_cast(f16x2, (W)), A);

#define STEP(ii, EL) { \
    const u32x4* pl4 = (const u32x4*)plds; \
    u32x4 R0 = pl4[0], R1 = pl4[1], R2 = pl4[2], R3 = pl4[3]; \
    u32x4 R4 = pl4[4], R5 = pl4[5], R6 = pl4[6], R7 = pl4[7]; \
    float A0 = 0.f, A1 = 0.f, A2 = 0.f, A3 = 0.f; \
    DOTQ(0,  R0.x, A0) DOTQ(1,  R0.y, A1) DOTQ(2,  R0.z, A2) DOTQ(3,  R0.w, A3) \
    DOTQ(4,  R1.x, A0) DOTQ(5,  R1.y, A1) DOTQ(6,  R1.z, A2) DOTQ(7,  R1.w, A3) \
    DOTQ(8,  R2.x, A0) DOTQ(9,  R2.y, A1) DOTQ(10, R2.z, A2) DOTQ(11, R2.w, A3) \
    DOTQ(12, R3.x, A0) DOTQ(13, R3.y, A1) DOTQ(14, R3.z, A2) DOTQ(15, R3.w, A3) \
    DOTQ(16, R4.x, A0) DOTQ(17, R4.y, A1) DOTQ(18, R4.z, A2) DOTQ(19, R4.w, A3) \
    DOTQ(20, R5.x, A0) DOTQ(21, R5.y, A1) DOTQ(22, R5.z, A2) DOTQ(23, R5.w, A3) \
    DOTQ(24, R6.x, A0) DOTQ(25, R6.y, A1) DOTQ(26, R6.z, A2) DOTQ(27, R6.w, A3) \
    DOTQ(28, R7.x, A0) DOTQ(29, R7.y, A1) DOTQ(30, R7.z, A2) DOTQ(31, R7.w, A3) \
    float s = (A0 + A1) + (A2 + A3); \
    float pn = s * (EL); \
    bool ok = (t0 + (ii)) < L; \
    pn = ok ? pn : pq; \
    unsigned sb = (unsigned)__builtin_amdgcn_readfirstlane((int)__float_as_uint(pn)); \
    int ee = ok ? ((int)((sb >> 23) & 255u) - 127) : 0; \
    Etot += ee; \
    float scl = __uint_as_float((unsigned)(127 - ee) << 23); \
    float qv = pn * scl; \
    _Float16 hq = (_Float16)qv; \
    pq = (float)hq; \
    plds[j] = hq; }

    // ---- sequential scan, chunks of CH=8 fully-unrolled steps ----
    for (int t0 = 1; t0 < L; t0 += CH) {
        // keep the 32 packed-E regs live (anti-spill anchors)
        asm volatile("" : "+v"(Eh0),  "+v"(Eh1),  "+v"(Eh2),  "+v"(Eh3),
                          "+v"(Eh4),  "+v"(Eh5),  "+v"(Eh6),  "+v"(Eh7),
                          "+v"(Eh8),  "+v"(Eh9),  "+v"(Eh10), "+v"(Eh11),
                          "+v"(Eh12), "+v"(Eh13), "+v"(Eh14), "+v"(Eh15));
        asm volatile("" : "+v"(Eh16), "+v"(Eh17), "+v"(Eh18), "+v"(Eh19),
                          "+v"(Eh20), "+v"(Eh21), "+v"(Eh22), "+v"(Eh23),
                          "+v"(Eh24), "+v"(Eh25), "+v"(Eh26), "+v"(Eh27),
                          "+v"(Eh28), "+v"(Eh29), "+v"(Eh30), "+v"(Eh31));

        // exp of current chunk's logits (off the critical p-chain)
        f32x4 el0, el1;
        el0.x = __expf(nl0.x); el0.y = __expf(nl0.y);
        el0.z = __expf(nl0.z); el0.w = __expf(nl0.w);
        el1.x = __expf(nl1.x); el1.y = __expf(nl1.y);
        el1.z = __expf(nl1.z); el1.w = __expf(nl1.w);

        // prefetch next chunk (consumed one full chunk later)
        {
            int tn = t0 + CH;
            int c0 = tn + 0; c0 = (c0 > TT - 1) ? TT - 1 : c0;
            int c1 = tn + 1; c1 = (c1 > TT - 1) ? TT - 1 : c1;
            int c2 = tn + 2; c2 = (c2 > TT - 1) ? TT - 1 : c2;
            int c3 = tn + 3; c3 = (c3 > TT - 1) ? TT - 1 : c3;
            int c4 = tn + 4; c4 = (c4 > TT - 1) ? TT - 1 : c4;
            int c5 = tn + 5; c5 = (c5 > TT - 1) ? TT - 1 : c5;
            int c6 = tn + 6; c6 = (c6 > TT - 1) ? TT - 1 : c6;
            int c7 = tn + 7; c7 = (c7 > TT - 1) ? TT - 1 : c7;
            nl0.x = lg[c0 * KK + j]; nl0.y = lg[c1 * KK + j];
            nl0.z = lg[c2 * KK + j]; nl0.w = lg[c3 * KK + j];
            nl1.x = lg[c4 * KK + j]; nl1.y = lg[c5 * KK + j];
            nl1.z = lg[c6 * KK + j]; nl1.w = lg[c7 * KK + j];
        }

        STEP(0, el0.x) STEP(1, el0.y) STEP(2, el0.z) STEP(3, el0.w)
        STEP(4, el1.x) STEP(5, el1.y) STEP(6, el1.z) STEP(7, el1.w)
    }
#undef STEP
#undef DOTQ

    float sump = wave_sum(pq);
    float third_b = mx + (float)Etot * 0.6931471805599453f + __logf(sump);
    float first_b = wave_sum(af);
    float second_b = wave_sum(asec);

    if (j == 0) {
        ws[b] = (third_b - first_b - second_b) * (1.0f / (float)BB);
    }
}

// Deterministic fixed-order reduction of the 1024 per-b contributions.
__global__ void crf_reduce(const float* __restrict__ ws, float* __restrict__ out) {
    int tid = threadIdx.x;  // 256 threads
    float v = ws[tid] + ws[tid + 256] + ws[tid + 512] + ws[tid + 768];
    v = wave_sum(v);
    __shared__ float sm[4];
    if ((tid & 63) == 0) sm[tid >> 6] = v;
    __syncthreads();
    if (tid == 0) out[0] = (sm[0] + sm[1]) + (sm[2] + sm[3]);
}

extern "C" void kernel_launch(void* const* d_in, const int* in_sizes, int n_in,
                              void* d_out, int out_size, void* d_ws, size_t ws_size,
                              hipStream_t stream) {
    const float* logits = (const float*)d_in[0];
    const float* trans  = (const float*)d_in[1];
    const int*   gold   = (const int*)d_in[2];
    const int*   slen   = (const int*)d_in[3];
    float* out = (float*)d_out;
    float* ws = (float*)d_ws;

    hipLaunchKernelGGL(crf_fwd, dim3(BB), dim3(64), 0, stream,
                       logits, trans, gold, slen, ws);
    hipLaunchKernelGGL(crf_reduce, dim3(1), dim3(256), 0, stream, ws, out);
}

// Round 13
// 95.030 us; speedup vs baseline: 1.3508x; 1.0902x over previous
//
#include <hip/hip_runtime.h>

#define BB 1024
#define TT 512
#define KK 64
#define CH 8   // scan steps per chunk

typedef _Float16 f16x2 __attribute__((ext_vector_type(2)));
typedef float f32x4 __attribute__((ext_vector_type(4)));
typedef unsigned int u32x4 __attribute__((ext_vector_type(4)));

__device__ __forceinline__ float wave_sum(float v) {
#pragma unroll
    for (int off = 1; off < 64; off <<= 1) v += __shfl_xor(v, off);
    return v;
}

__device__ __forceinline__ float wave_max(float v) {
#pragma unroll
    for (int off = 1; off < 64; off <<= 1) v = fmaxf(v, __shfl_xor(v, off));
    return v;
}

#if __has_builtin(__builtin_amdgcn_fdot2)
#define FDOT2(E, P, A) __builtin_amdgcn_fdot2((E), (P), (A), false)
#else
__device__ __forceinline__ float fdot2_emul(f16x2 e, f16x2 p, float a) {
    return fmaf((float)e.x, (float)p.x, fmaf((float)e.y, (float)p.y, a));
}
#define FDOT2(E, P, A) fdot2_emul((E), (P), (A))
#endif

// quad_perm DPP lane exchange (xor-1 / xor-2 within each 4-lane quad) — pure
// VALU, no LDS traffic.
#if __has_builtin(__builtin_amdgcn_mov_dpp)
__device__ __forceinline__ float dpp_xor1_f(float x) {
    return __uint_as_float((unsigned)__builtin_amdgcn_mov_dpp(
        (int)__float_as_uint(x), 0xB1, 0xF, 0xF, true));  // [1,0,3,2]
}
__device__ __forceinline__ float dpp_xor2_f(float x) {
    return __uint_as_float((unsigned)__builtin_amdgcn_mov_dpp(
        (int)__float_as_uint(x), 0x4E, 0xF, 0xF, true));  // [2,3,0,1]
}
#else
__device__ __forceinline__ float dpp_xor1_f(float x) { return __shfl_xor(x, 1); }
__device__ __forceinline__ float dpp_xor2_f(float x) { return __shfl_xor(x, 2); }
#endif

// One wave per batch element; lane j owns state j. 1 wave/SIMD at grid=1024.
// p kept in LDS as f16 with PER-STEP IN-CHAIN pow-2 rescale (round-11 proven;
// round-12's lag-1 fold overflowed f16 — data-dependent normalization must
// stay in-chain). New this round: 4-way k-slice. Lane j reads only its
// 16-value p slice (2 ds_read_b128 instead of 8 -> 4x less LDS return
// traffic), computes partials for the 4 rows of its quad (same 32 fdot2),
// then a 2-stage quad_perm-DPP reduce-scatter leaves lane j with row j's
// full sum. E fragment per lane: quad rows x own k-slice.
__global__ void __launch_bounds__(64)
__attribute__((amdgpu_waves_per_eu(1, 1)))
crf_fwd(
    const float* __restrict__ logits,
    const float* __restrict__ trans,
    const int* __restrict__ gold,
    const int* __restrict__ seq_len,
    float* __restrict__ ws)
{
    __shared__ __align__(16) _Float16 plds[KK];   // p broadcast buffer (f16)
    const int b = blockIdx.x;
    const int j = threadIdx.x & 63;
    const float* lg = logits + (size_t)b * (TT * KK);
    const int* gd = gold + (size_t)b * TT;
    const int L = seq_len[b];

    const int quad_r = (j >> 2) << 2;     // base row of my quad
    const int slice_c = (j & 3) << 4;     // base col of my 16-wide k-slice
    const bool lodd = (j & 1) != 0;
    const bool lhi  = (j & 2) != 0;

    // ---- Phase A: lane-parallel first & second terms (off the scan) ----
    float af = 0.0f, asec = 0.0f;
#pragma unroll
    for (int c = 0; c < TT / 64; ++c) {
        int t = c * 64 + j;
        if (t < L) {
            int g0 = gd[t];
            af += lg[t * KK + g0];
            if (t + 1 < L) {
                int g1 = gd[t + 1];
                asec += trans[g0 * KK + g1];
            }
        }
    }

    // ---- E fragment: rows quad_r..quad_r+3 x cols slice_c..slice_c+15,
    //      exp()'d and packed into 32 named f16x2 regs ----
    f16x2 Eh0, Eh1, Eh2, Eh3, Eh4, Eh5, Eh6, Eh7;
    f16x2 Eh8, Eh9, Eh10, Eh11, Eh12, Eh13, Eh14, Eh15;
    f16x2 Eh16, Eh17, Eh18, Eh19, Eh20, Eh21, Eh22, Eh23;
    f16x2 Eh24, Eh25, Eh26, Eh27, Eh28, Eh29, Eh30, Eh31;
#define MKP(DST, a, bgt) { DST.x = (_Float16)__expf(a); DST.y = (_Float16)__expf(bgt); }
#define DECROW(rr, N0, N1, N2, N3, N4, N5, N6, N7) { \
    const float* row_ = trans + (size_t)(quad_r + (rr)) * KK + slice_c; \
    f32x4 v0 = *(const f32x4*)(row_ + 0);  f32x4 v1 = *(const f32x4*)(row_ + 4); \
    f32x4 v2 = *(const f32x4*)(row_ + 8);  f32x4 v3 = *(const f32x4*)(row_ + 12); \
    MKP(N0, v0.x, v0.y) MKP(N1, v0.z, v0.w) MKP(N2, v1.x, v1.y) MKP(N3, v1.z, v1.w) \
    MKP(N4, v2.x, v2.y) MKP(N5, v2.z, v2.w) MKP(N6, v3.x, v3.y) MKP(N7, v3.z, v3.w) }
    DECROW(0, Eh0,  Eh1,  Eh2,  Eh3,  Eh4,  Eh5,  Eh6,  Eh7)
    DECROW(1, Eh8,  Eh9,  Eh10, Eh11, Eh12, Eh13, Eh14, Eh15)
    DECROW(2, Eh16, Eh17, Eh18, Eh19, Eh20, Eh21, Eh22, Eh23)
    DECROW(3, Eh24, Eh25, Eh26, Eh27, Eh28, Eh29, Eh30, Eh31)
#undef DECROW
#undef MKP

    // ---- t = 0 init ----
    float a0 = lg[j];
    float mx = wave_max(a0);
    float p0 = __expf(a0 - mx);          // in (0, 1], fits f16
    plds[j] = (_Float16)p0;
    int Etot = 0;

    // ---- preload chunk 0 (t = 1..8) ----
    f32x4 nl0, nl1;
    nl0.x = lg[1 * KK + j]; nl0.y = lg[2 * KK + j];
    nl0.z = lg[3 * KK + j]; nl0.w = lg[4 * KK + j];
    nl1.x = lg[5 * KK + j]; nl1.y = lg[6 * KK + j];
    nl1.z = lg[7 * KK + j]; nl1.w = lg[8 * KK + j];

    const u32x4* myslice = (const u32x4*)((const char*)plds + ((j & 3) << 5));

#define DOTW(EH, W, A) A = FDOT2(EH, __builtin_bit_cast(f16x2, (W)), A);

    // One recursion step: 2 slice reads -> 32 dots (4 rows x 8) -> quad
    // reduce-scatter (DPP) -> in-chain pow-2 rescale -> f16 store.
#define STEP(EL) { \
    u32x4 Ra = myslice[0], Rb = myslice[1]; \
    float A0 = 0.f, A1 = 0.f, A2 = 0.f, A3 = 0.f; \
    float A4 = 0.f, A5 = 0.f, A6 = 0.f, A7 = 0.f; \
    DOTW(Eh0,  Ra.x, A0) DOTW(Eh1,  Ra.y, A1) DOTW(Eh2,  Ra.z, A0) DOTW(Eh3,  Ra.w, A1) \
    DOTW(Eh4,  Rb.x, A0) DOTW(Eh5,  Rb.y, A1) DOTW(Eh6,  Rb.z, A0) DOTW(Eh7,  Rb.w, A1) \
    DOTW(Eh8,  Ra.x, A2) DOTW(Eh9,  Ra.y, A3) DOTW(Eh10, Ra.z, A2) DOTW(Eh11, Ra.w, A3) \
    DOTW(Eh12, Rb.x, A2) DOTW(Eh13, Rb.y, A3) DOTW(Eh14, Rb.z, A2) DOTW(Eh15, Rb.w, A3) \
    DOTW(Eh16, Ra.x, A4) DOTW(Eh17, Ra.y, A5) DOTW(Eh18, Ra.z, A4) DOTW(Eh19, Ra.w, A5) \
    DOTW(Eh20, Rb.x, A4) DOTW(Eh21, Rb.y, A5) DOTW(Eh22, Rb.z, A4) DOTW(Eh23, Rb.w, A5) \
    DOTW(Eh24, Ra.x, A6) DOTW(Eh25, Ra.y, A7) DOTW(Eh26, Ra.z, A6) DOTW(Eh27, Ra.w, A7) \
    DOTW(Eh28, Rb.x, A6) DOTW(Eh29, Rb.y, A7) DOTW(Eh30, Rb.z, A6) DOTW(Eh31, Rb.w, A7) \
    float P0 = A0 + A1, P1 = A2 + A3, P2 = A4 + A5, P3 = A6 + A7; \
    float S0 = lodd ? P0 : P1, K0 = lodd ? P1 : P0; \
    float S1 = lodd ? P2 : P3, K1 = lodd ? P3 : P2; \
    float Q0 = K0 + dpp_xor1_f(S0); \
    float Q1 = K1 + dpp_xor1_f(S1); \
    float S2 = lhi ? Q0 : Q1, K2 = lhi ? Q1 : Q0; \
    float s_ = K2 + dpp_xor2_f(S2); \
    float pn = s_ * (EL); \
    unsigned sb = (unsigned)__builtin_amdgcn_readfirstlane((int)__float_as_uint(pn)); \
    int ee = (int)((sb >> 23) & 255u) - 127; \
    Etot += ee; \
    float scl = __uint_as_float((unsigned)((127 - ee) << 23)); \
    plds[j] = (_Float16)(pn * scl); }

    // ---- main loop: full chunks only (all CH steps strictly < L) ----
    int t0 = 1;
    for (; t0 + CH <= L; t0 += CH) {
        // keep the 32 packed-E regs live (anti-spill anchors)
        asm volatile("" : "+v"(Eh0),  "+v"(Eh1),  "+v"(Eh2),  "+v"(Eh3),
                          "+v"(Eh4),  "+v"(Eh5),  "+v"(Eh6),  "+v"(Eh7),
                          "+v"(Eh8),  "+v"(Eh9),  "+v"(Eh10), "+v"(Eh11),
                          "+v"(Eh12), "+v"(Eh13), "+v"(Eh14), "+v"(Eh15));
        asm volatile("" : "+v"(Eh16), "+v"(Eh17), "+v"(Eh18), "+v"(Eh19),
                          "+v"(Eh20), "+v"(Eh21), "+v"(Eh22), "+v"(Eh23),
                          "+v"(Eh24), "+v"(Eh25), "+v"(Eh26), "+v"(Eh27),
                          "+v"(Eh28), "+v"(Eh29), "+v"(Eh30), "+v"(Eh31));

        // exp of current chunk's logits (off the critical p-chain)
        f32x4 el0, el1;
        el0.x = __expf(nl0.x); el0.y = __expf(nl0.y);
        el0.z = __expf(nl0.z); el0.w = __expf(nl0.w);
        el1.x = __expf(nl1.x); el1.y = __expf(nl1.y);
        el1.z = __expf(nl1.z); el1.w = __expf(nl1.w);

        // prefetch next chunk (consumed one full chunk later; also feeds the
        // remainder steps after the last full chunk)
        {
            int tn = t0 + CH;
            int c0 = tn + 0; c0 = (c0 > TT - 1) ? TT - 1 : c0;
            int c1 = tn + 1; c1 = (c1 > TT - 1) ? TT - 1 : c1;
            int c2 = tn + 2; c2 = (c2 > TT - 1) ? TT - 1 : c2;
            int c3 = tn + 3; c3 = (c3 > TT - 1) ? TT - 1 : c3;
            int c4 = tn + 4; c4 = (c4 > TT - 1) ? TT - 1 : c4;
            int c5 = tn + 5; c5 = (c5 > TT - 1) ? TT - 1 : c5;
            int c6 = tn + 6; c6 = (c6 > TT - 1) ? TT - 1 : c6;
            int c7 = tn + 7; c7 = (c7 > TT - 1) ? TT - 1 : c7;
            nl0.x = lg[c0 * KK + j]; nl0.y = lg[c1 * KK + j];
            nl0.z = lg[c2 * KK + j]; nl0.w = lg[c3 * KK + j];
            nl1.x = lg[c4 * KK + j]; nl1.y = lg[c5 * KK + j];
            nl1.z = lg[c6 * KK + j]; nl1.w = lg[c7 * KK + j];
        }

        STEP(el0.x) STEP(el0.y) STEP(el0.z) STEP(el0.w)
        STEP(el1.x) STEP(el1.y) STEP(el1.z) STEP(el1.w)
    }

    // ---- remainder: at most CH-1 steps, wave-uniform guards ----
    if (t0 < L) {
        f32x4 el0, el1;
        el0.x = __expf(nl0.x); el0.y = __expf(nl0.y);
        el0.z = __expf(nl0.z); el0.w = __expf(nl0.w);
        el1.x = __expf(nl1.x); el1.y = __expf(nl1.y);
        el1.z = __expf(nl1.z); el1.w = __expf(nl1.w);
        if (t0 + 0 < L) { STEP(el0.x) }
        if (t0 + 1 < L) { STEP(el0.y) }
        if (t0 + 2 < L) { STEP(el0.z) }
        if (t0 + 3 < L) { STEP(el0.w) }
        if (t0 + 4 < L) { STEP(el1.x) }
        if (t0 + 5 < L) { STEP(el1.y) }
        if (t0 + 6 < L) { STEP(el1.z) }
    }
#undef STEP
#undef DOTW

    float pfin = (float)plds[j];
    float sump = wave_sum(pfin);
    float third_b = mx + (float)Etot * 0.6931471805599453f + __logf(sump);
    float first_b = wave_sum(af);
    float second_b = wave_sum(asec);

    if (j == 0) {
        ws[b] = (third_b - first_b - second_b) * (1.0f / (float)BB);
    }
}

// Deterministic fixed-order reduction of the 1024 per-b contributions.
__global__ void crf_reduce(const float* __restrict__ ws, float* __restrict__ out) {
    int tid = threadIdx.x;  // 256 threads
    float v = ws[tid] + ws[tid + 256] + ws[tid + 512] + ws[tid + 768];
    v = wave_sum(v);
    __shared__ float sm[4];
    if ((tid & 63) == 0) sm[tid >> 6] = v;
    __syncthreads();
    if (tid == 0) out[0] = (sm[0] + sm[1]) + (sm[2] + sm[3]);
}

extern "C" void kernel_launch(void* const* d_in, const int* in_sizes, int n_in,
                              void* d_out, int out_size, void* d_ws, size_t ws_size,
                              hipStream_t stream) {
    const float* logits = (const float*)d_in[0];
    const float* trans  = (const float*)d_in[1];
    const int*   gold   = (const int*)d_in[2];
    const int*   slen   = (const int*)d_in[3];
    float* out = (float*)d_out;
    float* ws = (float*)d_ws;

    hipLaunchKernelGGL(crf_fwd, dim3(BB), dim3(64), 0, stream,
                       logits, trans, gold, slen, ws);
    hipLaunchKernelGGL(crf_reduce, dim3(1), dim3(256), 0, stream, ws, out);
}